// Round 1
// baseline (342.610 us; speedup 1.0000x reference)
//
#include <hip/hip_runtime.h>

// GINConv: out = (1+eps)*feat + segment_sum(feat[edge_src], edge_dst)
// N=100000 nodes, D=64 features (fp32), E=1200000 edges.
//
// Round 1: correctness-first baseline.
//   Kernel A: out[i,:] = (1+eps)*feat[i,:]   (float4-vectorized)
//   Kernel B: one wave (64 lanes) per edge; lane d does
//             atomicAdd(&out[dst*64+d], feat[src*64+d])
//   Coalesced 256B gather per wave; coalesced atomic burst per wave.

#define N_NODES 100000
#define D_FEAT  64
#define N_EDGES 1200000

__global__ __launch_bounds__(256) void gin_init_kernel(
    const float* __restrict__ feat,
    const float* __restrict__ eps,
    float* __restrict__ out)
{
    const float scale = 1.0f + eps[0];
    int i = blockIdx.x * blockDim.x + threadIdx.x;
    const int total4 = (N_NODES * D_FEAT) / 4;  // divisible: 64/4=16 per row
    if (i < total4) {
        float4 v = reinterpret_cast<const float4*>(feat)[i];
        v.x *= scale; v.y *= scale; v.z *= scale; v.w *= scale;
        reinterpret_cast<float4*>(out)[i] = v;
    }
}

__global__ __launch_bounds__(256) void gin_scatter_kernel(
    const float* __restrict__ feat,
    const int* __restrict__ edge_src,
    const int* __restrict__ edge_dst,
    float* __restrict__ out)
{
    // 4 waves per block, one edge per wave, lane = feature index.
    const int edge = blockIdx.x * 4 + (threadIdx.x >> 6);
    const int lane = threadIdx.x & 63;
    if (edge < N_EDGES) {
        const int src = edge_src[edge];
        const int dst = edge_dst[edge];
        const float v = feat[src * D_FEAT + lane];
        atomicAdd(&out[dst * D_FEAT + lane], v);
    }
}

extern "C" void kernel_launch(void* const* d_in, const int* in_sizes, int n_in,
                              void* d_out, int out_size, void* d_ws, size_t ws_size,
                              hipStream_t stream)
{
    const float* feat     = (const float*)d_in[0];
    const float* eps      = (const float*)d_in[1];
    const int*   edge_src = (const int*)d_in[2];
    const int*   edge_dst = (const int*)d_in[3];
    float* out = (float*)d_out;

    // Kernel A: initialize out = (1+eps)*feat  (harness poisons d_out each call)
    {
        const int total4 = (N_NODES * D_FEAT) / 4;
        const int block = 256;
        const int grid = (total4 + block - 1) / block;
        gin_init_kernel<<<grid, block, 0, stream>>>(feat, eps, out);
    }

    // Kernel B: scatter-add messages. One wave per edge.
    {
        const int edges_per_block = 4;  // 256 threads / 64 lanes
        const int grid = (N_EDGES + edges_per_block - 1) / edges_per_block;
        gin_scatter_kernel<<<grid, 256, 0, stream>>>(feat, edge_src, edge_dst, out);
    }
}

// Round 2
// 242.762 us; speedup vs baseline: 1.4113x; 1.4113x over previous
//
#include <hip/hip_runtime.h>

// GINConv: out = (1+eps)*feat + segment_sum(feat[edge_src], edge_dst)
// N=100000 nodes, D=64 features (fp32), E=1200000 edges.
//
// Round 2: eliminate fp32 global atomics (round 1: 76.8M memory-side atomics,
// WRITE_SIZE 307 MB = 12x over-write of out). Strategy:
//   K1 init:   out = (1+eps)*feat                       (float4)
//   K2 fill:   bucket edges by dst into ws:
//              pos = atomicAdd(cnt[dst],1); slots[dst*CAP+pos] = src
//              (int atomics at L2; CAP=64 >> Poisson(12) tail; overflow
//               falls back to direct fp32 atomics — statistically never)
//   K3 gather: one wave per node, lane = feature; sum feat rows of
//              in-neighbors from slots, single non-atomic out[node] += sum.
// Fp32 atomic count: 76.8M -> ~0. Heavy traffic becomes cache-served reads.

#define N_NODES 100000
#define D_FEAT  64
#define N_EDGES 1200000
#define CAP     64   // slots per node; degree ~ Poisson(12), P(>=64) ~ 1e-24

__global__ __launch_bounds__(256) void gin_init_kernel(
    const float* __restrict__ feat,
    const float* __restrict__ eps,
    float* __restrict__ out)
{
    const float scale = 1.0f + eps[0];
    int i = blockIdx.x * blockDim.x + threadIdx.x;
    const int total4 = (N_NODES * D_FEAT) / 4;
    if (i < total4) {
        float4 v = reinterpret_cast<const float4*>(feat)[i];
        v.x *= scale; v.y *= scale; v.z *= scale; v.w *= scale;
        reinterpret_cast<float4*>(out)[i] = v;
    }
}

__global__ __launch_bounds__(256) void gin_fill_kernel(
    const int* __restrict__ edge_src,
    const int* __restrict__ edge_dst,
    int* __restrict__ cnt,
    int* __restrict__ slots,
    const float* __restrict__ feat,
    float* __restrict__ out)
{
    int e = blockIdx.x * blockDim.x + threadIdx.x;
    if (e >= N_EDGES) return;
    const int dst = edge_dst[e];
    const int src = edge_src[e];
    const int pos = atomicAdd(&cnt[dst], 1);
    if (pos < CAP) {
        slots[dst * CAP + pos] = src;
    } else {
        // statistically-never overflow path; out already holds (1+eps)*feat
        for (int d = 0; d < D_FEAT; ++d)
            atomicAdd(&out[dst * D_FEAT + d], feat[src * D_FEAT + d]);
    }
}

__global__ __launch_bounds__(256) void gin_gather_kernel(
    const float* __restrict__ feat,
    const int* __restrict__ cnt,
    const int* __restrict__ slots,
    float* __restrict__ out)
{
    const int node = blockIdx.x * 4 + (threadIdx.x >> 6);
    const int lane = threadIdx.x & 63;
    if (node >= N_NODES) return;
    int n = cnt[node];
    if (n > CAP) n = CAP;
    const int* __restrict__ sl = slots + node * CAP;

    float sum0 = 0.0f, sum1 = 0.0f;
    int j = 0;
    for (; j + 2 <= n; j += 2) {          // 2-way unroll for load ILP
        const int s0 = sl[j];
        const int s1 = sl[j + 1];
        sum0 += feat[s0 * D_FEAT + lane];
        sum1 += feat[s1 * D_FEAT + lane];
    }
    if (j < n) sum0 += feat[sl[j] * D_FEAT + lane];

    out[node * D_FEAT + lane] += sum0 + sum1;  // single owner, no atomic
}

// ---- round-1 fallback (used only if ws_size is too small) ----
__global__ __launch_bounds__(256) void gin_scatter_kernel(
    const float* __restrict__ feat,
    const int* __restrict__ edge_src,
    const int* __restrict__ edge_dst,
    float* __restrict__ out)
{
    const int edge = blockIdx.x * 4 + (threadIdx.x >> 6);
    const int lane = threadIdx.x & 63;
    if (edge < N_EDGES) {
        const int src = edge_src[edge];
        const int dst = edge_dst[edge];
        atomicAdd(&out[dst * D_FEAT + lane], feat[src * D_FEAT + lane]);
    }
}

extern "C" void kernel_launch(void* const* d_in, const int* in_sizes, int n_in,
                              void* d_out, int out_size, void* d_ws, size_t ws_size,
                              hipStream_t stream)
{
    const float* feat     = (const float*)d_in[0];
    const float* eps      = (const float*)d_in[1];
    const int*   edge_src = (const int*)d_in[2];
    const int*   edge_dst = (const int*)d_in[3];
    float* out = (float*)d_out;

    // K1: out = (1+eps)*feat
    {
        const int total4 = (N_NODES * D_FEAT) / 4;
        gin_init_kernel<<<(total4 + 255) / 256, 256, 0, stream>>>(feat, eps, out);
    }

    const size_t need = (size_t)4 * (N_NODES + (size_t)N_NODES * CAP);  // ~26 MB
    if (ws_size >= need) {
        int* cnt   = (int*)d_ws;            // [N_NODES]
        int* slots = cnt + N_NODES;         // [N_NODES * CAP]

        hipMemsetAsync(cnt, 0, N_NODES * sizeof(int), stream);

        gin_fill_kernel<<<(N_EDGES + 255) / 256, 256, 0, stream>>>(
            edge_src, edge_dst, cnt, slots, feat, out);

        gin_gather_kernel<<<(N_NODES + 3) / 4, 256, 0, stream>>>(
            feat, cnt, slots, out);
    } else {
        // fallback: atomic scatter (round-1 path)
        gin_scatter_kernel<<<(N_EDGES + 3) / 4, 256, 0, stream>>>(
            feat, edge_src, edge_dst, out);
    }
}

// Round 4
// 217.759 us; speedup vs baseline: 1.5733x; 1.1148x over previous
//
#include <hip/hip_runtime.h>

// GINConv: out = (1+eps)*feat + segment_sum(feat[edge_src], edge_dst)
// N=100000, D=64 fp32, E=1200000.
//
// Round 4 = round 3 + correctness fix:
//   __shfl (ds_bpermute) from an EXEC-inactive lane is UNDEFINED. Round 3 put
//   the shfl inside `if (j < n)`, so when j < n but source lane j was itself
//   inactive (its own j0+(j>>4) >= n), garbage was broadcast (absmax 6.3).
//   Fix: execute the shfl with all 64 lanes active (clamped source index),
//   guard only the dependent feat load/accumulate.

#define N_NODES 100000
#define D_FEAT  64
#define N_EDGES 1200000
#define CAP     64
#define OVF_CAP 4096

__global__ __launch_bounds__(256) void gin_fill_kernel(
    const int* __restrict__ edge_src,
    const int* __restrict__ edge_dst,
    int* __restrict__ cnt,
    int* __restrict__ slots,
    int* __restrict__ ovf_cnt,
    int* __restrict__ ovf)
{
    const int base = (blockIdx.x * 256 + threadIdx.x) * 4;
    if (base + 4 <= N_EDGES) {
        const int4 s4 = *reinterpret_cast<const int4*>(&edge_src[base]);
        const int4 d4 = *reinterpret_cast<const int4*>(&edge_dst[base]);
        // issue all 4 atomics up front -> 4 independent latency chains
        const int p0 = atomicAdd(&cnt[d4.x], 1);
        const int p1 = atomicAdd(&cnt[d4.y], 1);
        const int p2 = atomicAdd(&cnt[d4.z], 1);
        const int p3 = atomicAdd(&cnt[d4.w], 1);
        if (p0 < CAP) slots[d4.x * CAP + p0] = s4.x;
        else { int o = atomicAdd(ovf_cnt, 1); if (o < OVF_CAP) { ovf[2*o] = s4.x; ovf[2*o+1] = d4.x; } }
        if (p1 < CAP) slots[d4.y * CAP + p1] = s4.y;
        else { int o = atomicAdd(ovf_cnt, 1); if (o < OVF_CAP) { ovf[2*o] = s4.y; ovf[2*o+1] = d4.y; } }
        if (p2 < CAP) slots[d4.z * CAP + p2] = s4.z;
        else { int o = atomicAdd(ovf_cnt, 1); if (o < OVF_CAP) { ovf[2*o] = s4.z; ovf[2*o+1] = d4.z; } }
        if (p3 < CAP) slots[d4.w * CAP + p3] = s4.w;
        else { int o = atomicAdd(ovf_cnt, 1); if (o < OVF_CAP) { ovf[2*o] = s4.w; ovf[2*o+1] = d4.w; } }
    } else {
        for (int e = base; e < N_EDGES; ++e) {
            const int src = edge_src[e];
            const int dst = edge_dst[e];
            const int p = atomicAdd(&cnt[dst], 1);
            if (p < CAP) slots[dst * CAP + p] = src;
            else { int o = atomicAdd(ovf_cnt, 1); if (o < OVF_CAP) { ovf[2*o] = src; ovf[2*o+1] = dst; } }
        }
    }
}

__global__ __launch_bounds__(256) void gin_gather_kernel(
    const float* __restrict__ feat,
    const float* __restrict__ eps,
    const int* __restrict__ cnt,
    const int* __restrict__ slots,
    float* __restrict__ out)
{
    const int node = blockIdx.x * 4 + (threadIdx.x >> 6);  // wave-uniform
    if (node >= N_NODES) return;                            // whole wave exits together
    const int lane = threadIdx.x & 63;
    const int r = lane >> 4;      // row-subgroup 0..3
    const int c = lane & 15;      // float4 column group 0..15

    int n = cnt[node];
    if (n > CAP) n = CAP;
    const int my_slot = slots[node * CAP + lane];   // coalesced 256B row

    float ax = 0.f, ay = 0.f, az = 0.f, aw = 0.f;
    for (int j0 = 0; j0 < n; j0 += 4) {             // n is wave-uniform: no loop divergence
        const int j = j0 + r;
        const int jj = (j < n) ? j : 0;             // clamp so shfl src is always valid
        const int s = __shfl(my_slot, jj);          // ALL 64 lanes active here
        if (j < n) {
            const float4 v = *reinterpret_cast<const float4*>(&feat[s * D_FEAT + 4 * c]);
            ax += v.x; ay += v.y; az += v.z; aw += v.w;
        }
    }
    // butterfly-reduce across the 4 row-subgroups (lane^16, lane^32)
    ax += __shfl_xor(ax, 16); ay += __shfl_xor(ay, 16);
    az += __shfl_xor(az, 16); aw += __shfl_xor(aw, 16);
    ax += __shfl_xor(ax, 32); ay += __shfl_xor(ay, 32);
    az += __shfl_xor(az, 32); aw += __shfl_xor(aw, 32);

    if (r == 0) {
        const float scale = 1.0f + eps[0];
        const float4 f = *reinterpret_cast<const float4*>(&feat[node * D_FEAT + 4 * c]);
        float4 res;
        res.x = scale * f.x + ax;
        res.y = scale * f.y + ay;
        res.z = scale * f.z + az;
        res.w = scale * f.w + aw;
        *reinterpret_cast<float4*>(&out[node * D_FEAT + 4 * c]) = res;  // only write of out
    }
}

__global__ __launch_bounds__(256) void gin_cleanup_kernel(
    const float* __restrict__ feat,
    const int* __restrict__ ovf_cnt,
    const int* __restrict__ ovf,
    float* __restrict__ out)
{
    int m = ovf_cnt[0];
    if (m > OVF_CAP) m = OVF_CAP;
    const int d = threadIdx.x & 63;
    for (int e = threadIdx.x >> 6; e < m; e += 4) {   // 4 waves, 1 block
        const int src = ovf[2*e], dst = ovf[2*e+1];
        atomicAdd(&out[dst * D_FEAT + d], feat[src * D_FEAT + d]);
    }
}

// ---- fallback path (ws too small): round-1 style ----
__global__ __launch_bounds__(256) void gin_init_kernel(
    const float* __restrict__ feat, const float* __restrict__ eps, float* __restrict__ out)
{
    const float scale = 1.0f + eps[0];
    int i = blockIdx.x * blockDim.x + threadIdx.x;
    if (i < (N_NODES * D_FEAT) / 4) {
        float4 v = reinterpret_cast<const float4*>(feat)[i];
        v.x *= scale; v.y *= scale; v.z *= scale; v.w *= scale;
        reinterpret_cast<float4*>(out)[i] = v;
    }
}
__global__ __launch_bounds__(256) void gin_scatter_kernel(
    const float* __restrict__ feat, const int* __restrict__ edge_src,
    const int* __restrict__ edge_dst, float* __restrict__ out)
{
    const int edge = blockIdx.x * 4 + (threadIdx.x >> 6);
    const int lane = threadIdx.x & 63;
    if (edge < N_EDGES)
        atomicAdd(&out[edge_dst[edge] * D_FEAT + lane], feat[edge_src[edge] * D_FEAT + lane]);
}

extern "C" void kernel_launch(void* const* d_in, const int* in_sizes, int n_in,
                              void* d_out, int out_size, void* d_ws, size_t ws_size,
                              hipStream_t stream)
{
    const float* feat     = (const float*)d_in[0];
    const float* eps      = (const float*)d_in[1];
    const int*   edge_src = (const int*)d_in[2];
    const int*   edge_dst = (const int*)d_in[3];
    float* out = (float*)d_out;

    // ws layout: cnt[N] | ovf_cnt[1] | ovf[2*OVF_CAP] | slots[N*CAP]
    const size_t need = sizeof(int) * ((size_t)N_NODES + 1 + 2 * OVF_CAP + (size_t)N_NODES * CAP);
    if (ws_size >= need) {
        int* cnt     = (int*)d_ws;
        int* ovf_cnt = cnt + N_NODES;
        int* ovf     = ovf_cnt + 1;
        int* slots   = ovf + 2 * OVF_CAP;

        hipMemsetAsync(cnt, 0, sizeof(int) * (N_NODES + 1), stream);  // cnt + ovf_cnt

        const int threads = (N_EDGES + 3) / 4;
        gin_fill_kernel<<<(threads + 255) / 256, 256, 0, stream>>>(
            edge_src, edge_dst, cnt, slots, ovf_cnt, ovf);

        gin_gather_kernel<<<N_NODES / 4, 256, 0, stream>>>(
            feat, eps, cnt, slots, out);

        gin_cleanup_kernel<<<1, 256, 0, stream>>>(feat, ovf_cnt, ovf, out);
    } else {
        const int total4 = (N_NODES * D_FEAT) / 4;
        gin_init_kernel<<<(total4 + 255) / 256, 256, 0, stream>>>(feat, eps, out);
        gin_scatter_kernel<<<(N_EDGES + 3) / 4, 256, 0, stream>>>(
            feat, edge_src, edge_dst, out);
    }
}